// Round 1
// baseline (165.345 us; speedup 1.0000x reference)
//
#include <hip/hip_runtime.h>

#define NH 32
#define KVHN 8
#define HD 128
#define QL 1024
#define MS 4096

typedef __bf16 bf16x8 __attribute__((ext_vector_type(8)));
typedef float f32x4 __attribute__((ext_vector_type(4)));

// ---------------- Kernel A: cache update (pure copy + slice override) ----------------
__global__ __launch_bounds__(256) void cache_update_kernel(
    const float4* __restrict__ kn, const float4* __restrict__ vn,
    const float4* __restrict__ pk, const float4* __restrict__ pv,
    const int* __restrict__ bp_p, const int* __restrict__ sp_p,
    float4* __restrict__ ok, float4* __restrict__ ov)
{
    int i = blockIdx.x * 256 + threadIdx.x;      // float4 index, 4,194,304 total
    int bp = *bp_p, sp = *sp_p;
    int d4  = i & 31;
    int pos = (i >> 5) & 4095;
    int kvh = (i >> 17) & 7;
    int b   = i >> 20;
    if (b == bp && pos >= sp && pos < sp + QL) {
        int ns = (kvh * QL + (pos - sp)) * 32 + d4;
        ok[i] = kn[ns];
        ov[i] = vn[ns];
    } else {
        ok[i] = pk[i];
        ov[i] = pv[i];
    }
}

// ---------------- Kernel B: GQA flash attention over updated cache ----------------
// grid = (16 qtiles, 32 heads), block = 256 (4 waves x 16 q-rows), KV tile = 32
__global__ __launch_bounds__(256) void attn_kernel(
    const float* __restrict__ q,
    const int* __restrict__ bp_p, const int* __restrict__ sp_p,
    const float* __restrict__ scale_p,
    const float* __restrict__ ck, const float* __restrict__ cv,
    float* __restrict__ out)
{
    // LDS: K tile [32][128] bf16 swizzled (8192 B) | V^T tile [128 rows][stride 80B] (10240 B)
    //      | P per-wave [16 rows][stride 80B] (4*1280 B)
    __shared__ __align__(16) unsigned char smem[8192 + 10240 + 5120];
    unsigned char* Ksm = smem;
    unsigned char* Vsm = smem + 8192;
    unsigned char* Psm = smem + 8192 + 10240;

    const int sp = *sp_p;
    const int bp = *bp_p;
    const float scl = *scale_p;

    const int head = blockIdx.y;
    const int kvh  = head >> 2;            // 4 q-heads per kv head
    const int q0   = blockIdx.x * 64;
    const int tid  = threadIdx.x;
    const int wave = tid >> 6;
    const int lane = tid & 63;
    const int g    = lane >> 4;            // 16-lane group id (0..3)
    const int c    = lane & 15;            // col-within-group
    const int qrw  = q0 + wave * 16;       // wave's base q row

    const float* kc_row = ck + (size_t)(bp * KVHN + kvh) * MS * HD;
    const float* vc_row = cv + (size_t)(bp * KVHN + kvh) * MS * HD;

    // ---- Q fragments (hoisted): A[m=c][k = kc*32 + g*8 + j] ----
    bf16x8 qf[4];
    #pragma unroll
    for (int kc = 0; kc < 4; ++kc) {
        const float* src = q + ((size_t)(head * QL + qrw + c) * HD + kc * 32 + g * 8);
        float4 f0 = *(const float4*)src;
        float4 f1 = *(const float4*)(src + 4);
        bf16x8 v;
        v[0]=(__bf16)f0.x; v[1]=(__bf16)f0.y; v[2]=(__bf16)f0.z; v[3]=(__bf16)f0.w;
        v[4]=(__bf16)f1.x; v[5]=(__bf16)f1.y; v[6]=(__bf16)f1.z; v[7]=(__bf16)f1.w;
        qf[kc] = v;
    }

    f32x4 acc[8];
    #pragma unroll
    for (int dt = 0; dt < 8; ++dt) {
        f32x4 z = {0.f, 0.f, 0.f, 0.f};
        acc[dt] = z;
    }
    float m_run[4], l_part[4];
    #pragma unroll
    for (int r = 0; r < 4; ++r) { m_run[r] = -1e30f; l_part[r] = 0.f; }

    const int kv_lim  = sp + q0 + 64;          // exclusive causal limit for this block
    const int n_iters = (kv_lim + 31) >> 5;

    for (int it = 0; it < n_iters; ++it) {
        const int n0 = it * 32;
        __syncthreads();   // previous iteration's LDS reads done before restaging

        // ---- stage K tile: rows pos, 16B chunks, chunk-XOR swizzle ----
        #pragma unroll
        for (int p = 0; p < 2; ++p) {
            int id  = tid + p * 256;
            int pl  = id >> 4;          // 0..31 (kv row in tile)
            int chk = id & 15;          // 16B chunk (8 bf16)
            const float* src = kc_row + (size_t)(n0 + pl) * HD + chk * 8;
            float4 f0 = *(const float4*)src;
            float4 f1 = *(const float4*)(src + 4);
            bf16x8 v;
            v[0]=(__bf16)f0.x; v[1]=(__bf16)f0.y; v[2]=(__bf16)f0.z; v[3]=(__bf16)f0.w;
            v[4]=(__bf16)f1.x; v[5]=(__bf16)f1.y; v[6]=(__bf16)f1.z; v[7]=(__bf16)f1.w;
            *(bf16x8*)(Ksm + pl * 256 + ((chk ^ (pl & 7)) << 4)) = v;
        }
        // ---- stage V^T tile: V_T[d][kv], row stride 80B (2-way banks, free) ----
        #pragma unroll
        for (int p = 0; p < 2; ++p) {
            int id = tid + p * 256;
            int d  = id & 127;
            int kg = id >> 7;           // kv group of 8 (0..3)
            const float* src = vc_row + (size_t)(n0 + kg * 8) * HD + d;
            bf16x8 v;
            #pragma unroll
            for (int j = 0; j < 8; ++j) v[j] = (__bf16)src[j * HD];
            *(bf16x8*)(Vsm + d * 80 + kg * 16) = v;
        }
        __syncthreads();

        // ---- QK^T: S[16q][32kv] = Q(16x128) . K^T(128x32), two 16-col tiles ----
        f32x4 st[2];
        #pragma unroll
        for (int nt = 0; nt < 2; ++nt) {
            f32x4 s = {0.f, 0.f, 0.f, 0.f};
            int pl = nt * 16 + c;       // kv row this lane supplies (B: n = c)
            #pragma unroll
            for (int kc = 0; kc < 4; ++kc) {
                bf16x8 kb = *(const bf16x8*)(Ksm + pl * 256 + (((kc * 4 + g) ^ (pl & 7)) << 4));
                s = __builtin_amdgcn_mfma_f32_16x16x32_bf16(qf[kc], kb, s, 0, 0, 0);
            }
            st[nt] = s;
        }

        // ---- mask + online softmax (rows 4g+r, cols n0+nt*16+c) ----
        #pragma unroll
        for (int r = 0; r < 4; ++r) {
            int qpos = sp + qrw + 4 * g + r;     // global position of this q row
            float s0 = (n0 + c      <= qpos) ? st[0][r] * scl : -1e30f;
            float s1 = (n0 + 16 + c <= qpos) ? st[1][r] * scl : -1e30f;
            float mx = fmaxf(s0, s1);
            mx = fmaxf(mx, __shfl_xor(mx, 1, 16));
            mx = fmaxf(mx, __shfl_xor(mx, 2, 16));
            mx = fmaxf(mx, __shfl_xor(mx, 4, 16));
            mx = fmaxf(mx, __shfl_xor(mx, 8, 16));
            float nm    = fmaxf(m_run[r], mx);
            float corrv = __expf(m_run[r] - nm);
            m_run[r] = nm;
            float p0 = __expf(s0 - nm);
            float p1 = __expf(s1 - nm);
            l_part[r] = l_part[r] * corrv + p0 + p1;
            #pragma unroll
            for (int dt = 0; dt < 8; ++dt) acc[dt][r] *= corrv;
            // P to LDS: P_lds[row=4g+r][col], stride 80B
            *(__bf16*)(Psm + wave * 1280 + (4 * g + r) * 80 + c * 2)        = (__bf16)p0;
            *(__bf16*)(Psm + wave * 1280 + (4 * g + r) * 80 + (16 + c) * 2) = (__bf16)p1;
        }

        // ---- PV: O(16x128) += P(16x32) . V(32x128) ----
        bf16x8 pa = *(const bf16x8*)(Psm + wave * 1280 + c * 80 + g * 16);  // A[m=c][k=8g+j]
        #pragma unroll
        for (int dt = 0; dt < 8; ++dt) {
            bf16x8 vb = *(const bf16x8*)(Vsm + (dt * 16 + c) * 80 + g * 16); // B[k=8g+j][n=c]
            acc[dt] = __builtin_amdgcn_mfma_f32_16x16x32_bf16(pa, vb, acc[dt], 0, 0, 0);
        }
    }

    // ---- epilogue: reduce denominators, normalize, store ----
    #pragma unroll
    for (int r = 0; r < 4; ++r) {
        float l = l_part[r];
        l += __shfl_xor(l, 1, 16);
        l += __shfl_xor(l, 2, 16);
        l += __shfl_xor(l, 4, 16);
        l += __shfl_xor(l, 8, 16);
        l_part[r] = 1.0f / l;
    }
    #pragma unroll
    for (int dt = 0; dt < 8; ++dt) {
        #pragma unroll
        for (int r = 0; r < 4; ++r) {
            out[(size_t)(qrw + 4 * g + r) * (NH * HD) + head * HD + dt * 16 + c] =
                acc[dt][r] * l_part[r];
        }
    }
}

// ---------------- launch ----------------
extern "C" void kernel_launch(void* const* d_in, const int* in_sizes, int n_in,
                              void* d_out, int out_size, void* d_ws, size_t ws_size,
                              hipStream_t stream)
{
    const float* q_st   = (const float*)d_in[0];
    const float* k_new  = (const float*)d_in[1];
    const float* v_new  = (const float*)d_in[2];
    // d_in[3] attn_mask: causal by construction, computed analytically in-kernel
    const int*   bp_p   = (const int*)d_in[4];
    const float* past_k = (const float*)d_in[5];
    const float* past_v = (const float*)d_in[6];
    const int*   sp_p   = (const int*)d_in[7];
    const float* scl_p  = (const float*)d_in[8];

    float* out_attn = (float*)d_out;                       // [1024][4096]
    float* out_k    = out_attn + (size_t)QL * NH * HD;     // [4][8][4096][128]
    float* out_v    = out_k + (size_t)4 * KVHN * MS * HD;

    cache_update_kernel<<<16384, 256, 0, stream>>>(
        (const float4*)k_new, (const float4*)v_new,
        (const float4*)past_k, (const float4*)past_v,
        bp_p, sp_p, (float4*)out_k, (float4*)out_v);

    dim3 grid(QL / 64, NH);
    attn_kernel<<<grid, 256, 0, stream>>>(
        q_st, bp_p, sp_p, scl_p, out_k, out_v, out_attn);
}

// Round 2
// 145.459 us; speedup vs baseline: 1.1367x; 1.1367x over previous
//
#include <hip/hip_runtime.h>

#define NH 32
#define KVHN 8
#define HD 128
#define QL 1024
#define MS 4096
#define KVB 64

typedef __bf16 bf16x8 __attribute__((ext_vector_type(8)));
typedef __bf16 bf16x4 __attribute__((ext_vector_type(4)));
typedef float f32x4 __attribute__((ext_vector_type(4)));

// ws layout: Kbf [8][4096][128] bf16 (8 MB) | Vt [8][128][4096] bf16 (8 MB)

// ---------------- Kernel A: cache update + fused bf16 K pack ----------------
__global__ __launch_bounds__(256) void cache_update_kernel(
    const float4* __restrict__ kn, const float4* __restrict__ vn,
    const float4* __restrict__ pk, const float4* __restrict__ pv,
    const int* __restrict__ bp_p, const int* __restrict__ sp_p,
    float4* __restrict__ ok, float4* __restrict__ ov,
    __bf16* __restrict__ kbf)
{
    int i = blockIdx.x * 256 + threadIdx.x;      // float4 index, 4,194,304 total
    int bp = *bp_p, sp = *sp_p;
    int d4  = i & 31;
    int pos = (i >> 5) & 4095;
    int kvh = (i >> 17) & 7;
    int b   = i >> 20;
    float4 kv4, vv4;
    if (b == bp && pos >= sp && pos < sp + QL) {
        int ns = (kvh * QL + (pos - sp)) * 32 + d4;
        kv4 = kn[ns]; vv4 = vn[ns];
    } else {
        kv4 = pk[i]; vv4 = pv[i];
    }
    ok[i] = kv4; ov[i] = vv4;
    if (b == bp) {
        bf16x4 o;
        o[0] = (__bf16)kv4.x; o[1] = (__bf16)kv4.y;
        o[2] = (__bf16)kv4.z; o[3] = (__bf16)kv4.w;
        *(bf16x4*)(kbf + ((size_t)kvh * MS + pos) * HD + d4 * 4) = o;
    }
}

// ---------------- Kernel B: V^T bf16 pack (LDS transpose, coalesced both sides) ----
// grid: 8 kvh * 64 pos-tiles = 512 blocks, 256 threads
__global__ __launch_bounds__(256) void v_transpose_kernel(
    const float* __restrict__ vn, const float* __restrict__ pv,
    const int* __restrict__ bp_p, const int* __restrict__ sp_p,
    __bf16* __restrict__ vt)
{
    __shared__ __bf16 tile[64][132];   // pad to 132 (264B rows, 8B aligned, banks spread)
    int blk = blockIdx.x;
    int kvh = blk >> 6;
    int pt  = blk & 63;
    int bp = *bp_p, sp = *sp_p;
    int r0 = threadIdx.x >> 2;          // 0..63 (pos within tile)
    int cb = (threadIdx.x & 3) * 32;    // col base
    int pos = pt * 64 + r0;
    const float* src = (pos >= sp && pos < sp + QL)
        ? vn + ((size_t)kvh * QL + (pos - sp)) * HD + cb
        : pv + (((size_t)(bp * KVHN) + kvh) * MS + pos) * HD + cb;
    #pragma unroll
    for (int j = 0; j < 8; ++j) {
        float4 f = *(const float4*)(src + j * 4);
        bf16x4 o;
        o[0] = (__bf16)f.x; o[1] = (__bf16)f.y; o[2] = (__bf16)f.z; o[3] = (__bf16)f.w;
        *(bf16x4*)(&tile[r0][cb + j * 4]) = o;
    }
    __syncthreads();
    #pragma unroll
    for (int p = 0; p < 4; ++p) {
        int u = threadIdx.x + p * 256;
        int d = u >> 3; int chk = u & 7;
        bf16x8 v;
        #pragma unroll
        for (int j = 0; j < 8; ++j) v[j] = tile[chk * 8 + j][d];
        *(bf16x8*)(vt + ((size_t)(kvh * HD) + d) * MS + pt * 64 + chk * 8) = v;
    }
}

// ---------------- Kernel C: GQA flash attention (bf16 K / V^T from ws) ----------------
// grid = (16 qtiles, 32 heads), block = 256 (4 waves x 16 q-rows), KV tile = 64
__global__ __launch_bounds__(256) void attn_kernel(
    const float* __restrict__ q,
    const int* __restrict__ bp_p, const int* __restrict__ sp_p,
    const float* __restrict__ scale_p,
    const __bf16* __restrict__ kbf, const __bf16* __restrict__ vt,
    float* __restrict__ out)
{
    // LDS: K [64 rows][256B] swizzled (16384) | V^T [128 rows][128B] swizzled (16384)
    //      | P per-wave [16][stride 144B] (4*2304)
    __shared__ __align__(16) unsigned char smem[16384 + 16384 + 9216];
    unsigned char* Ksm = smem;
    unsigned char* Vsm = smem + 16384;
    unsigned char* Psm = smem + 32768;

    const int sp = *sp_p;
    const float scl = *scale_p;

    const int head = blockIdx.y;
    const int kvh  = head >> 2;
    const int q0   = blockIdx.x * 64;
    const int tid  = threadIdx.x;
    const int wave = tid >> 6;
    const int lane = tid & 63;
    const int g    = lane >> 4;
    const int c    = lane & 15;
    const int qrw  = q0 + wave * 16;

    const __bf16* krow = kbf + (size_t)kvh * MS * HD;
    const __bf16* vrow = vt  + (size_t)kvh * HD * MS;

    // ---- Q fragments (hoisted): A[m=c][k = kc*32 + g*8 + j] ----
    bf16x8 qf[4];
    #pragma unroll
    for (int kc = 0; kc < 4; ++kc) {
        const float* src = q + ((size_t)(head * QL + qrw + c) * HD + kc * 32 + g * 8);
        float4 f0 = *(const float4*)src;
        float4 f1 = *(const float4*)(src + 4);
        bf16x8 v;
        v[0]=(__bf16)f0.x; v[1]=(__bf16)f0.y; v[2]=(__bf16)f0.z; v[3]=(__bf16)f0.w;
        v[4]=(__bf16)f1.x; v[5]=(__bf16)f1.y; v[6]=(__bf16)f1.z; v[7]=(__bf16)f1.w;
        qf[kc] = v;
    }

    f32x4 acc[8];
    #pragma unroll
    for (int dt = 0; dt < 8; ++dt) { f32x4 z = {0.f,0.f,0.f,0.f}; acc[dt] = z; }
    float m_run[4], l_part[4];
    #pragma unroll
    for (int r = 0; r < 4; ++r) { m_run[r] = -1e30f; l_part[r] = 0.f; }

    const int kv_lim  = sp + q0 + 64;
    const int n_iters = (kv_lim + KVB - 1) / KVB;

    for (int it = 0; it < n_iters; ++it) {
        const int n0 = it * KVB;
        __syncthreads();

        // ---- stage K tile [64][128] bf16: 1024 16B units, chunk-XOR swizzle ----
        #pragma unroll
        for (int p = 0; p < 4; ++p) {
            int u  = tid + p * 256;
            int pl = u >> 4;            // kv row 0..63
            int ch = u & 15;            // 16B chunk
            bf16x8 v = *(const bf16x8*)(krow + (size_t)(n0 + pl) * HD + ch * 8);
            *(bf16x8*)(Ksm + pl * 256 + ((ch ^ (pl & 7)) << 4)) = v;
        }
        // ---- stage V^T tile [128][64] bf16: 1024 16B units, chunk-XOR swizzle ----
        #pragma unroll
        for (int p = 0; p < 4; ++p) {
            int u = tid + p * 256;
            int d = u >> 3;             // d row 0..127
            int ch = u & 7;             // 16B chunk (8 kv)
            bf16x8 v = *(const bf16x8*)(vrow + (size_t)d * MS + n0 + ch * 8);
            *(bf16x8*)(Vsm + d * 128 + ((ch ^ (d & 7)) << 4)) = v;
        }
        __syncthreads();

        // ---- QK^T: S[16q][64kv], 4 col-tiles x 4 k-chunks ----
        f32x4 st[4];
        #pragma unroll
        for (int nt = 0; nt < 4; ++nt) {
            f32x4 s = {0.f,0.f,0.f,0.f};
            int pl = nt * 16 + c;
            #pragma unroll
            for (int kc = 0; kc < 4; ++kc) {
                bf16x8 kb = *(const bf16x8*)(Ksm + pl * 256 + (((kc * 4 + g) ^ (pl & 7)) << 4));
                s = __builtin_amdgcn_mfma_f32_16x16x32_bf16(qf[kc], kb, s, 0, 0, 0);
            }
            st[nt] = s;
        }

        // ---- mask + online softmax with defer-max (THR=8) ----
        #pragma unroll
        for (int r = 0; r < 4; ++r) {
            int qpos = sp + qrw + 4 * g + r;
            float sv[4];
            #pragma unroll
            for (int nt = 0; nt < 4; ++nt)
                sv[nt] = (n0 + nt * 16 + c <= qpos) ? st[nt][r] * scl : -1e30f;
            float mx = fmaxf(fmaxf(sv[0], sv[1]), fmaxf(sv[2], sv[3]));
            mx = fmaxf(mx, __shfl_xor(mx, 1, 16));
            mx = fmaxf(mx, __shfl_xor(mx, 2, 16));
            mx = fmaxf(mx, __shfl_xor(mx, 4, 16));
            mx = fmaxf(mx, __shfl_xor(mx, 8, 16));
            if (!__all(mx <= m_run[r] + 8.0f)) {
                float nm = fmaxf(m_run[r], mx);
                float corrv = __expf(m_run[r] - nm);
                m_run[r] = nm;
                l_part[r] *= corrv;
                #pragma unroll
                for (int dt = 0; dt < 8; ++dt) acc[dt][r] *= corrv;
            }
            float lsum = 0.f;
            #pragma unroll
            for (int nt = 0; nt < 4; ++nt) {
                float pp = __expf(sv[nt] - m_run[r]);
                lsum += pp;
                *(__bf16*)(Psm + wave * 2304 + (4 * g + r) * 144 + (nt * 16 + c) * 2) = (__bf16)pp;
            }
            l_part[r] += lsum;
        }

        // ---- PV: O(16x128) += P(16x64) . V(64x128) ----
        bf16x8 pa[2];
        #pragma unroll
        for (int kk = 0; kk < 2; ++kk)
            pa[kk] = *(const bf16x8*)(Psm + wave * 2304 + c * 144 + (kk * 32 + g * 8) * 2);
        #pragma unroll
        for (int dt = 0; dt < 8; ++dt) {
            int vr = dt * 16 + c;
            #pragma unroll
            for (int kk = 0; kk < 2; ++kk) {
                bf16x8 vb = *(const bf16x8*)(Vsm + vr * 128 + (((kk * 4 + g) ^ (vr & 7)) << 4));
                acc[dt] = __builtin_amdgcn_mfma_f32_16x16x32_bf16(pa[kk], vb, acc[dt], 0, 0, 0);
            }
        }
    }

    // ---- epilogue ----
    #pragma unroll
    for (int r = 0; r < 4; ++r) {
        float l = l_part[r];
        l += __shfl_xor(l, 1, 16);
        l += __shfl_xor(l, 2, 16);
        l += __shfl_xor(l, 4, 16);
        l += __shfl_xor(l, 8, 16);
        l_part[r] = 1.0f / l;
    }
    #pragma unroll
    for (int dt = 0; dt < 8; ++dt) {
        #pragma unroll
        for (int r = 0; r < 4; ++r) {
            out[(size_t)(qrw + 4 * g + r) * (NH * HD) + head * HD + dt * 16 + c] =
                acc[dt][r] * l_part[r];
        }
    }
}

// ---------------- launch ----------------
extern "C" void kernel_launch(void* const* d_in, const int* in_sizes, int n_in,
                              void* d_out, int out_size, void* d_ws, size_t ws_size,
                              hipStream_t stream)
{
    const float* q_st   = (const float*)d_in[0];
    const float* k_new  = (const float*)d_in[1];
    const float* v_new  = (const float*)d_in[2];
    const int*   bp_p   = (const int*)d_in[4];
    const float* past_k = (const float*)d_in[5];
    const float* past_v = (const float*)d_in[6];
    const int*   sp_p   = (const int*)d_in[7];
    const float* scl_p  = (const float*)d_in[8];

    float* out_attn = (float*)d_out;                       // [1024][4096]
    float* out_k    = out_attn + (size_t)QL * NH * HD;     // [4][8][4096][128]
    float* out_v    = out_k + (size_t)4 * KVHN * MS * HD;

    __bf16* kbf = (__bf16*)d_ws;                           // [8][4096][128]
    __bf16* vtw = kbf + (size_t)KVHN * MS * HD;            // [8][128][4096]

    cache_update_kernel<<<16384, 256, 0, stream>>>(
        (const float4*)k_new, (const float4*)v_new,
        (const float4*)past_k, (const float4*)past_v,
        bp_p, sp_p, (float4*)out_k, (float4*)out_v, kbf);

    v_transpose_kernel<<<512, 256, 0, stream>>>(
        v_new, past_v, bp_p, sp_p, vtw);

    dim3 grid(QL / 64, NH);
    attn_kernel<<<grid, 256, 0, stream>>>(
        q_st, bp_p, sp_p, scl_p, kbf, vtw, out_attn);
}

// Round 3
// 139.702 us; speedup vs baseline: 1.1836x; 1.0412x over previous
//
#include <hip/hip_runtime.h>

#define NH 32
#define KVHN 8
#define HD 128
#define QL 1024
#define MS 4096
#define KVB 64

typedef __bf16 bf16x8 __attribute__((ext_vector_type(8)));
typedef __bf16 bf16x4 __attribute__((ext_vector_type(4)));
typedef float f32x4 __attribute__((ext_vector_type(4)));

// ws: Kbf [8][4096][128] bf16, rows pre-swizzled (chunk ^= pos&7)      (8 MB)
//     Vt  [8][64 tiles][128 d][64 kv] bf16, pre-swizzled (chunk ^= d&7) (8 MB)

__device__ __forceinline__ void gload16(const void* g, void* l) {
    __builtin_amdgcn_global_load_lds(
        (const __attribute__((address_space(1))) unsigned int*)g,
        (__attribute__((address_space(3))) unsigned int*)l, 16, 0, 0);
}

// ---------------- Kernel A: cache update + fused swizzled bf16 K pack ----------------
__global__ __launch_bounds__(256) void cache_update_kernel(
    const float4* __restrict__ kn, const float4* __restrict__ vn,
    const float4* __restrict__ pk, const float4* __restrict__ pv,
    const int* __restrict__ bp_p, const int* __restrict__ sp_p,
    float4* __restrict__ ok, float4* __restrict__ ov,
    __bf16* __restrict__ kbf)
{
    int i = blockIdx.x * 256 + threadIdx.x;      // float4 index, 4,194,304 total
    int bp = *bp_p, sp = *sp_p;
    int d4  = i & 31;
    int pos = (i >> 5) & 4095;
    int kvh = (i >> 17) & 7;
    int b   = i >> 20;
    float4 kv4, vv4;
    if (b == bp && pos >= sp && pos < sp + QL) {
        int ns = (kvh * QL + (pos - sp)) * 32 + d4;
        kv4 = kn[ns]; vv4 = vn[ns];
    } else {
        kv4 = pk[i]; vv4 = pv[i];
    }
    ok[i] = kv4; ov[i] = vv4;
    if (b == bp) {
        bf16x4 o;
        o[0] = (__bf16)kv4.x; o[1] = (__bf16)kv4.y;
        o[2] = (__bf16)kv4.z; o[3] = (__bf16)kv4.w;
        int c16 = d4 >> 1, half = d4 & 1;
        *(bf16x4*)(kbf + ((size_t)kvh * MS + pos) * HD
                       + ((c16 ^ (pos & 7)) * 8 + half * 4)) = o;
    }
}

// ---------------- Kernel B: V^T swizzled bf16 pack (tile-contiguous) ----------------
// grid: 8 kvh * 64 pos-tiles = 512 blocks, 256 threads
__global__ __launch_bounds__(256) void v_transpose_kernel(
    const float* __restrict__ vn, const float* __restrict__ pv,
    const int* __restrict__ bp_p, const int* __restrict__ sp_p,
    __bf16* __restrict__ vt)
{
    __shared__ __bf16 tile[64][132];
    int blk = blockIdx.x;
    int kvh = blk >> 6;
    int pt  = blk & 63;
    int bp = *bp_p, sp = *sp_p;
    int r0 = threadIdx.x >> 2;          // 0..63 (pos within tile)
    int cb = (threadIdx.x & 3) * 32;    // col base
    int pos = pt * 64 + r0;
    const float* src = (pos >= sp && pos < sp + QL)
        ? vn + ((size_t)kvh * QL + (pos - sp)) * HD + cb
        : pv + (((size_t)(bp * KVHN) + kvh) * MS + pos) * HD + cb;
    #pragma unroll
    for (int j = 0; j < 8; ++j) {
        float4 f = *(const float4*)(src + j * 4);
        bf16x4 o;
        o[0] = (__bf16)f.x; o[1] = (__bf16)f.y; o[2] = (__bf16)f.z; o[3] = (__bf16)f.w;
        *(bf16x4*)(&tile[r0][cb + j * 4]) = o;
    }
    __syncthreads();
    #pragma unroll
    for (int p = 0; p < 4; ++p) {
        int u = threadIdx.x + p * 256;
        int d = u >> 3; int chk = u & 7;
        bf16x8 v;
        #pragma unroll
        for (int j = 0; j < 8; ++j) v[j] = tile[chk * 8 + j][d];
        // tile-contiguous [kvh][pt][d][64], chunk pre-swizzled by d&7
        *(bf16x8*)(vt + (((size_t)kvh * 64 + pt) * HD + d) * 64
                      + ((chk ^ (d & 7)) * 8)) = v;
    }
}

// ---------------- Kernel C: GQA flash attention, async-staged double-buffer ----------
// grid = 512 (balanced), block = 256 (4 waves x 16 q-rows), KV tile = 64
__global__ __launch_bounds__(256) void attn_kernel(
    const float* __restrict__ q,
    const int* __restrict__ sp_p,
    const float* __restrict__ scale_p,
    const __bf16* __restrict__ kbf, const __bf16* __restrict__ vt,
    float* __restrict__ out)
{
    // LDS: buf0 {K 16K | V 16K} | buf1 {K 16K | V 16K} | P 4x2304
    __shared__ __align__(16) unsigned char smem[65536 + 9216];
    unsigned char* Psm = smem + 65536;

    const int sp = *sp_p;
    const float scl = *scale_p;

    // balanced 1D grid: CU pairs a long block with a short one
    int bid = blockIdx.x;
    int head = bid >> 4;
    int qt = bid & 15;
    int qtile = (bid >= 256) ? (15 - qt) : qt;

    const int kvh  = head >> 2;
    const int q0   = qtile * 64;
    const int tid  = threadIdx.x;
    const int wave = tid >> 6;
    const int lane = tid & 63;
    const int g    = lane >> 4;
    const int c    = lane & 15;
    const int qrw  = q0 + wave * 16;

    const unsigned char* krow = (const unsigned char*)(kbf + (size_t)kvh * MS * HD);
    const unsigned char* vrow = (const unsigned char*)(vt + (size_t)kvh * 64 * HD * 64);

    // ---- Q fragments (hoisted, scale folded): A[m=c][k = kc*32 + g*8 + j] ----
    bf16x8 qf[4];
    #pragma unroll
    for (int kc = 0; kc < 4; ++kc) {
        const float* src = q + ((size_t)(head * QL + qrw + c) * HD + kc * 32 + g * 8);
        float4 f0 = *(const float4*)src;
        float4 f1 = *(const float4*)(src + 4);
        bf16x8 v;
        v[0]=(__bf16)(f0.x*scl); v[1]=(__bf16)(f0.y*scl);
        v[2]=(__bf16)(f0.z*scl); v[3]=(__bf16)(f0.w*scl);
        v[4]=(__bf16)(f1.x*scl); v[5]=(__bf16)(f1.y*scl);
        v[6]=(__bf16)(f1.z*scl); v[7]=(__bf16)(f1.w*scl);
        qf[kc] = v;
    }

    f32x4 acc[8];
    #pragma unroll
    for (int dt = 0; dt < 8; ++dt) { f32x4 z = {0.f,0.f,0.f,0.f}; acc[dt] = z; }
    float m_run[4], l_part[4];
    #pragma unroll
    for (int r = 0; r < 4; ++r) { m_run[r] = -1e30f; l_part[r] = 0.f; }

    const int kv_lim  = sp + q0 + 64;
    const int n_iters = (kv_lim + KVB - 1) / KVB;

    // per-thread stage of one KV tile: 8 x global_load_lds dwordx4 (pure DMA)
    auto stage = [&](int buf, int t) {
        const unsigned char* kt = krow + (size_t)t * 16384;   // K tile, contiguous 16KB
        const unsigned char* vtile = vrow + (size_t)t * 16384; // V tile, contiguous 16KB
        unsigned char* kl = smem + buf * 32768;
        unsigned char* vl = kl + 16384;
        #pragma unroll
        for (int p = 0; p < 4; ++p) {
            int off = (wave * 4 + p) * 1024;
            gload16(kt + off + lane * 16, kl + off);
            gload16(vtile + off + lane * 16, vl + off);
        }
    };

    int cur = 0;
    stage(0, 0);
    __syncthreads();

    for (int it = 0; it < n_iters; ++it) {
        const int n0 = it * KVB;
        if (it + 1 < n_iters) stage(cur ^ 1, it + 1);

        const unsigned char* Ksm = smem + cur * 32768;
        const unsigned char* Vsm = Ksm + 16384;

        // ---- QK^T: S[16q][64kv], 4 col-tiles x 4 k-chunks ----
        f32x4 st[4];
        #pragma unroll
        for (int nt = 0; nt < 4; ++nt) {
            f32x4 s = {0.f,0.f,0.f,0.f};
            int pl = nt * 16 + c;
            #pragma unroll
            for (int kc = 0; kc < 4; ++kc) {
                bf16x8 kb = *(const bf16x8*)(Ksm + pl * 256 + (((kc * 4 + g) ^ (pl & 7)) << 4));
                s = __builtin_amdgcn_mfma_f32_16x16x32_bf16(qf[kc], kb, s, 0, 0, 0);
            }
            st[nt] = s;
        }

        // ---- softmax with defer-max (THR=8); mask only on diagonal tiles ----
        const bool need_mask = (n0 + KVB - 1) > (sp + qrw);
        #pragma unroll
        for (int r = 0; r < 4; ++r) {
            float sv[4];
            if (need_mask) {
                int qpos = sp + qrw + 4 * g + r;
                #pragma unroll
                for (int nt = 0; nt < 4; ++nt)
                    sv[nt] = (n0 + nt * 16 + c <= qpos) ? st[nt][r] : -1e30f;
            } else {
                #pragma unroll
                for (int nt = 0; nt < 4; ++nt) sv[nt] = st[nt][r];
            }
            float mx = fmaxf(fmaxf(sv[0], sv[1]), fmaxf(sv[2], sv[3]));
            mx = fmaxf(mx, __shfl_xor(mx, 1, 16));
            mx = fmaxf(mx, __shfl_xor(mx, 2, 16));
            mx = fmaxf(mx, __shfl_xor(mx, 4, 16));
            mx = fmaxf(mx, __shfl_xor(mx, 8, 16));
            if (!__all(mx <= m_run[r] + 8.0f)) {
                float nm = fmaxf(m_run[r], mx);
                float corrv = __expf(m_run[r] - nm);
                m_run[r] = nm;
                l_part[r] *= corrv;
                #pragma unroll
                for (int dt = 0; dt < 8; ++dt) acc[dt][r] *= corrv;
            }
            float lsum = 0.f;
            #pragma unroll
            for (int nt = 0; nt < 4; ++nt) {
                float pp = __expf(sv[nt] - m_run[r]);
                lsum += pp;
                *(__bf16*)(Psm + wave * 2304 + (4 * g + r) * 144 + (nt * 16 + c) * 2) = (__bf16)pp;
            }
            l_part[r] += lsum;
        }

        // ---- PV: O(16x128) += P(16x64) . V(64x128) ----
        bf16x8 pa[2];
        #pragma unroll
        for (int kk = 0; kk < 2; ++kk)
            pa[kk] = *(const bf16x8*)(Psm + wave * 2304 + c * 144 + (kk * 32 + g * 8) * 2);
        #pragma unroll
        for (int dt = 0; dt < 8; ++dt) {
            int vr = dt * 16 + c;
            #pragma unroll
            for (int kk = 0; kk < 2; ++kk) {
                bf16x8 vb = *(const bf16x8*)(Vsm + vr * 128 + (((kk * 4 + g) ^ (vr & 7)) << 4));
                acc[dt] = __builtin_amdgcn_mfma_f32_16x16x32_bf16(pa[kk], vb, acc[dt], 0, 0, 0);
            }
        }

        __syncthreads();   // drains vmcnt (next tile landed) + LDS-read fence
        cur ^= 1;
    }

    // ---- epilogue ----
    #pragma unroll
    for (int r = 0; r < 4; ++r) {
        float l = l_part[r];
        l += __shfl_xor(l, 1, 16);
        l += __shfl_xor(l, 2, 16);
        l += __shfl_xor(l, 4, 16);
        l += __shfl_xor(l, 8, 16);
        l_part[r] = 1.0f / l;
    }
    #pragma unroll
    for (int dt = 0; dt < 8; ++dt) {
        #pragma unroll
        for (int r = 0; r < 4; ++r) {
            out[(size_t)(qrw + 4 * g + r) * (NH * HD) + head * HD + dt * 16 + c] =
                acc[dt][r] * l_part[r];
        }
    }
}

// ---------------- launch ----------------
extern "C" void kernel_launch(void* const* d_in, const int* in_sizes, int n_in,
                              void* d_out, int out_size, void* d_ws, size_t ws_size,
                              hipStream_t stream)
{
    const float* q_st   = (const float*)d_in[0];
    const float* k_new  = (const float*)d_in[1];
    const float* v_new  = (const float*)d_in[2];
    const int*   bp_p   = (const int*)d_in[4];
    const float* past_k = (const float*)d_in[5];
    const float* past_v = (const float*)d_in[6];
    const int*   sp_p   = (const int*)d_in[7];
    const float* scl_p  = (const float*)d_in[8];

    float* out_attn = (float*)d_out;                       // [1024][4096]
    float* out_k    = out_attn + (size_t)QL * NH * HD;     // [4][8][4096][128]
    float* out_v    = out_k + (size_t)4 * KVHN * MS * HD;

    __bf16* kbf = (__bf16*)d_ws;                           // [8][4096][128] swizzled
    __bf16* vtw = kbf + (size_t)KVHN * MS * HD;            // [8][64][128][64] swizzled

    cache_update_kernel<<<16384, 256, 0, stream>>>(
        (const float4*)k_new, (const float4*)v_new,
        (const float4*)past_k, (const float4*)past_v,
        bp_p, sp_p, (float4*)out_k, (float4*)out_v, kbf);

    v_transpose_kernel<<<512, 256, 0, stream>>>(
        v_new, past_v, bp_p, sp_p, vtw);

    attn_kernel<<<512, 256, 0, stream>>>(
        q_st, sp_p, scl_p, kbf, vtw, out_attn);
}

// Round 4
// 131.443 us; speedup vs baseline: 1.2579x; 1.0628x over previous
//
#include <hip/hip_runtime.h>

#define NH 32
#define KVHN 8
#define HD 128
#define QL 1024
#define MS 4096
#define KVB 64

typedef __bf16 bf16x8 __attribute__((ext_vector_type(8)));
typedef __bf16 bf16x4 __attribute__((ext_vector_type(4)));
typedef float f32x4 __attribute__((ext_vector_type(4)));
typedef float f32x16 __attribute__((ext_vector_type(16)));

// ws: Kbf [8][4096][128] bf16, rows pre-swizzled (chunk16 ^= pos&7)      (8 MB)
//     Vt  [8][64 tiles][128 d][64 kv] bf16, pre-swizzled (chunk ^= d&7)  (8 MB)

__device__ __forceinline__ void gload16(const void* g, void* l) {
    __builtin_amdgcn_global_load_lds(
        (const __attribute__((address_space(1))) unsigned int*)g,
        (__attribute__((address_space(3))) unsigned int*)l, 16, 0, 0);
}

__device__ __forceinline__ unsigned int pk2(float a, float b) {
    union { __bf16 h; unsigned short u; } x, y;
    x.h = (__bf16)a; y.h = (__bf16)b;
    return (unsigned int)x.u | ((unsigned int)y.u << 16);
}

// ---------------- Kernel A: cache update + fused swizzled bf16 K pack ----------------
__global__ __launch_bounds__(256) void cache_update_kernel(
    const float4* __restrict__ kn, const float4* __restrict__ vn,
    const float4* __restrict__ pk, const float4* __restrict__ pv,
    const int* __restrict__ bp_p, const int* __restrict__ sp_p,
    float4* __restrict__ ok, float4* __restrict__ ov,
    __bf16* __restrict__ kbf)
{
    int i = blockIdx.x * 256 + threadIdx.x;      // float4 index, 4,194,304 total
    int bp = *bp_p, sp = *sp_p;
    int d4  = i & 31;
    int pos = (i >> 5) & 4095;
    int kvh = (i >> 17) & 7;
    int b   = i >> 20;
    float4 kv4, vv4;
    if (b == bp && pos >= sp && pos < sp + QL) {
        int ns = (kvh * QL + (pos - sp)) * 32 + d4;
        kv4 = kn[ns]; vv4 = vn[ns];
    } else {
        kv4 = pk[i]; vv4 = pv[i];
    }
    ok[i] = kv4; ov[i] = vv4;
    if (b == bp) {
        bf16x4 o;
        o[0] = (__bf16)kv4.x; o[1] = (__bf16)kv4.y;
        o[2] = (__bf16)kv4.z; o[3] = (__bf16)kv4.w;
        int c16 = d4 >> 1, half = d4 & 1;
        *(bf16x4*)(kbf + ((size_t)kvh * MS + pos) * HD
                       + ((c16 ^ (pos & 7)) * 8 + half * 4)) = o;
    }
}

// ---------------- Kernel B: V^T swizzled bf16 pack (tile-contiguous) ----------------
__global__ __launch_bounds__(256) void v_transpose_kernel(
    const float* __restrict__ vn, const float* __restrict__ pv,
    const int* __restrict__ bp_p, const int* __restrict__ sp_p,
    __bf16* __restrict__ vt)
{
    __shared__ __bf16 tile[64][132];
    int blk = blockIdx.x;
    int kvh = blk >> 6;
    int pt  = blk & 63;
    int bp = *bp_p, sp = *sp_p;
    int r0 = threadIdx.x >> 2;          // 0..63 (pos within tile)
    int cb = (threadIdx.x & 3) * 32;    // col base
    int pos = pt * 64 + r0;
    const float* src = (pos >= sp && pos < sp + QL)
        ? vn + ((size_t)kvh * QL + (pos - sp)) * HD + cb
        : pv + (((size_t)(bp * KVHN) + kvh) * MS + pos) * HD + cb;
    #pragma unroll
    for (int j = 0; j < 8; ++j) {
        float4 f = *(const float4*)(src + j * 4);
        bf16x4 o;
        o[0] = (__bf16)f.x; o[1] = (__bf16)f.y; o[2] = (__bf16)f.z; o[3] = (__bf16)f.w;
        *(bf16x4*)(&tile[r0][cb + j * 4]) = o;
    }
    __syncthreads();
    #pragma unroll
    for (int p = 0; p < 4; ++p) {
        int u = threadIdx.x + p * 256;
        int d = u >> 3; int chk = u & 7;
        bf16x8 v;
        #pragma unroll
        for (int j = 0; j < 8; ++j) v[j] = tile[chk * 8 + j][d];
        *(bf16x8*)(vt + (((size_t)kvh * 64 + pt) * HD + d) * 64
                      + ((chk ^ (d & 7)) * 8)) = v;
    }
}

// ---------------- Kernel C: swapped-operand 32x32 flash attention ----------------
// grid = 512, block = 128 (2 waves x 32 q-rows), KV tile = 64, dbuf LDS
__global__ __launch_bounds__(128, 1) void attn_kernel(
    const float* __restrict__ q,
    const int* __restrict__ sp_p,
    const float* __restrict__ scale_p,
    const __bf16* __restrict__ kbf, const __bf16* __restrict__ vt,
    float* __restrict__ out)
{
    __shared__ __align__(16) unsigned char smem[65536];   // 2 x {K 16K | V 16K}

    const int sp = *sp_p;
    const float scl = *scale_p;

    int bid = blockIdx.x;
    int head = bid >> 4;
    int qt = bid & 15;
    int qtile = (bid >= 256) ? (15 - qt) : qt;

    const int kvh  = head >> 2;
    const int q0   = qtile * 64;
    const int tid  = threadIdx.x;
    const int wave = tid >> 6;          // 0..1
    const int lane = tid & 63;
    const int hi   = lane >> 5;         // half id
    const int c31  = lane & 31;
    const int qb   = q0 + wave * 32;    // wave's first q row
    const int myq  = qb + c31;          // this lane's q column (softmax state owner)

    const unsigned char* krow = (const unsigned char*)(kbf + (size_t)kvh * MS * HD);
    const unsigned char* vrow = (const unsigned char*)(vt + (size_t)kvh * 64 * HD * 64);

    // ---- Q B-fragments (hoisted, scale folded): B[k=d][n=q], n=c31, k=hi*8+j (+16*dc)
    bf16x8 qf[8];
    #pragma unroll
    for (int dc = 0; dc < 8; ++dc) {
        const float* src = q + ((size_t)(head * QL + qb + c31) * HD + dc * 16 + hi * 8);
        float4 f0 = *(const float4*)src;
        float4 f1 = *(const float4*)(src + 4);
        bf16x8 v;
        v[0]=(__bf16)(f0.x*scl); v[1]=(__bf16)(f0.y*scl);
        v[2]=(__bf16)(f0.z*scl); v[3]=(__bf16)(f0.w*scl);
        v[4]=(__bf16)(f1.x*scl); v[5]=(__bf16)(f1.y*scl);
        v[6]=(__bf16)(f1.z*scl); v[7]=(__bf16)(f1.w*scl);
        qf[dc] = v;
    }

    f32x16 acc[4];                       // O[q=crow(reg,hi)][d=dsub*32+c31]
    #pragma unroll
    for (int dsub = 0; dsub < 4; ++dsub)
        #pragma unroll
        for (int r = 0; r < 16; ++r) acc[dsub][r] = 0.f;
    float m_run = -1e30f, l_run = 0.f;

    const int n_iters = (sp + q0 + 64) / KVB;

    auto stage = [&](int buf, int t) {
        const unsigned char* kt = krow + (size_t)t * 16384;
        const unsigned char* vtile = vrow + (size_t)t * 16384;
        unsigned char* kl = smem + buf * 32768;
        unsigned char* vl = kl + 16384;
        #pragma unroll
        for (int p = 0; p < 8; ++p) {
            int off = p * 2048 + tid * 16;
            gload16(kt + off, kl + off);
            gload16(vtile + off, vl + off);
        }
    };

    int cur = 0;
    stage(0, 0);
    __syncthreads();

    for (int it = 0; it < n_iters; ++it) {
        const int n0 = it * KVB;
        if (it + 1 < n_iters) stage(cur ^ 1, it + 1);

        const unsigned char* Ksm = smem + cur * 32768;
        const unsigned char* Vsm = Ksm + 16384;

        // ---- QK^T (swapped): st[s] = K(32kv x 128d) . Q^T(128d x 32q) ----
        f32x16 st[2];
        #pragma unroll
        for (int s = 0; s < 2; ++s) {
            #pragma unroll
            for (int r = 0; r < 16; ++r) st[s][r] = 0.f;
            int kr = s * 32 + c31;
            #pragma unroll
            for (int dc = 0; dc < 8; ++dc) {
                bf16x8 kf = *(const bf16x8*)(Ksm + kr * 256 + (((2 * dc + hi) ^ (kr & 7)) << 4));
                st[s] = __builtin_amdgcn_mfma_f32_32x32x16_bf16(kf, qf[dc], st[s], 0, 0, 0);
            }
        }

        // ---- mask + in-register row max ----
        const bool need_mask = (n0 + KVB - 1) > (sp + qb);
        float mx = -1e30f;
        #pragma unroll
        for (int s = 0; s < 2; ++s) {
            #pragma unroll
            for (int r = 0; r < 16; ++r) {
                if (need_mask) {
                    int kvg = n0 + s * 32 + (r & 3) + 8 * (r >> 2) + 4 * hi;
                    if (kvg > sp + myq) st[s][r] = -1e30f;
                }
                mx = fmaxf(mx, st[s][r]);
            }
        }
        mx = fmaxf(mx, __shfl_xor(mx, 32));

        // ---- defer-max rescale (rare) ----
        if (!__all(mx <= m_run + 8.0f)) {
            float nm = fmaxf(m_run, mx);
            float corr = __expf(m_run - nm);
            m_run = nm;
            l_run *= corr;
            #pragma unroll
            for (int r = 0; r < 16; ++r) {
                int qsrc = (r & 3) + 8 * (r >> 2) + 4 * hi;
                float cq = __shfl(corr, qsrc);
                acc[0][r] *= cq; acc[1][r] *= cq; acc[2][r] *= cq; acc[3][r] *= cq;
            }
        }

        // ---- exp + sum (in-register) ----
        float lsum = 0.f;
        #pragma unroll
        for (int s = 0; s < 2; ++s)
            #pragma unroll
            for (int r = 0; r < 16; ++r) {
                float pv = __expf(st[s][r] - m_run);
                st[s][r] = pv;
                lsum += pv;
            }
        l_run += lsum;

        // ---- pack P to bf16 quads: loQ = regs {0-3,8-11}, hiQ = regs {4-7,12-15} ----
        unsigned int loW[8], hiW[8];
        #pragma unroll
        for (int s = 0; s < 2; ++s)
            #pragma unroll
            for (int qd = 0; qd < 2; ++qd) {
                int ks = s * 2 + qd;
                int b = qd * 8;
                loW[ks*2+0] = pk2(st[s][b+0], st[s][b+1]);
                loW[ks*2+1] = pk2(st[s][b+2], st[s][b+3]);
                hiW[ks*2+0] = pk2(st[s][b+4], st[s][b+5]);
                hiW[ks*2+1] = pk2(st[s][b+6], st[s][b+7]);
            }

        // ---- exchange across lane halves, assemble PA frags A[m=q][k=kv] ----
        bf16x8 pfrag[4];
        #pragma unroll
        for (int ks = 0; ks < 4; ++ks) {
            unsigned int own0 = hi ? hiW[ks*2+0] : loW[ks*2+0];
            unsigned int own1 = hi ? hiW[ks*2+1] : loW[ks*2+1];
            unsigned int xm0  = hi ? loW[ks*2+0] : hiW[ks*2+0];
            unsigned int xm1  = hi ? loW[ks*2+1] : hiW[ks*2+1];
            unsigned int rc0 = __shfl_xor(xm0, 32);
            unsigned int rc1 = __shfl_xor(xm1, 32);
            union { unsigned int u[4]; bf16x8 v; } fu;
            fu.u[0] = hi ? rc0 : own0;    // j0..3  (from half 0)
            fu.u[1] = hi ? rc1 : own1;
            fu.u[2] = hi ? own0 : rc0;    // j4..7  (from half 1)
            fu.u[3] = hi ? own1 : rc1;
            pfrag[ks] = fu.v;
        }

        // ---- PV: O(32q x 128d) += P(32x64) . V(64x128) ----
        #pragma unroll
        for (int dsub = 0; dsub < 4; ++dsub) {
            int vr = dsub * 32 + c31;
            #pragma unroll
            for (int ks = 0; ks < 4; ++ks) {
                bf16x8 vf = *(const bf16x8*)(Vsm + vr * 128 + (((ks * 2 + hi) ^ (vr & 7)) << 4));
                acc[dsub] = __builtin_amdgcn_mfma_f32_32x32x16_bf16(pfrag[ks], vf, acc[dsub], 0, 0, 0);
            }
        }

        __syncthreads();
        cur ^= 1;
    }

    // ---- epilogue ----
    l_run += __shfl_xor(l_run, 32);
    float linv = 1.0f / l_run;
    #pragma unroll
    for (int r = 0; r < 16; ++r) {
        int qsrc = (r & 3) + 8 * (r >> 2) + 4 * hi;
        float lq = __shfl(linv, qsrc);
        float* orow = out + (size_t)(qb + qsrc) * (NH * HD) + head * HD;
        orow[ 0 + c31] = acc[0][r] * lq;
        orow[32 + c31] = acc[1][r] * lq;
        orow[64 + c31] = acc[2][r] * lq;
        orow[96 + c31] = acc[3][r] * lq;
    }
}

// ---------------- launch ----------------
extern "C" void kernel_launch(void* const* d_in, const int* in_sizes, int n_in,
                              void* d_out, int out_size, void* d_ws, size_t ws_size,
                              hipStream_t stream)
{
    const float* q_st   = (const float*)d_in[0];
    const float* k_new  = (const float*)d_in[1];
    const float* v_new  = (const float*)d_in[2];
    const int*   bp_p   = (const int*)d_in[4];
    const float* past_k = (const float*)d_in[5];
    const float* past_v = (const float*)d_in[6];
    const int*   sp_p   = (const int*)d_in[7];
    const float* scl_p  = (const float*)d_in[8];

    float* out_attn = (float*)d_out;                       // [1024][4096]
    float* out_k    = out_attn + (size_t)QL * NH * HD;     // [4][8][4096][128]
    float* out_v    = out_k + (size_t)4 * KVHN * MS * HD;

    __bf16* kbf = (__bf16*)d_ws;                           // [8][4096][128] swizzled
    __bf16* vtw = kbf + (size_t)KVHN * MS * HD;            // [8][64][128][64] swizzled

    cache_update_kernel<<<16384, 256, 0, stream>>>(
        (const float4*)k_new, (const float4*)v_new,
        (const float4*)past_k, (const float4*)past_v,
        bp_p, sp_p, (float4*)out_k, (float4*)out_v, kbf);

    v_transpose_kernel<<<512, 256, 0, stream>>>(
        v_new, past_v, bp_p, sp_p, vtw);

    attn_kernel<<<512, 128, 0, stream>>>(
        q_st, sp_p, scl_p, kbf, vtw, out_attn);
}

// Round 6
// 109.892 us; speedup vs baseline: 1.5046x; 1.1961x over previous
//
#include <hip/hip_runtime.h>

#define NH 32
#define KVHN 8
#define HD 128
#define QL 1024
#define MS 4096
#define KVB 64

typedef __bf16 bf16x8 __attribute__((ext_vector_type(8)));
typedef __bf16 bf16x4 __attribute__((ext_vector_type(4)));
typedef float f32x4 __attribute__((ext_vector_type(4)));
typedef float f32x16 __attribute__((ext_vector_type(16)));

// ws: Kbf [8][4096][128] bf16, rows pre-swizzled (chunk16 ^= pos&7)      (8 MB)
//     Vt  [8][64 tiles][128 d][64 kv] bf16, pre-swizzled (chunk ^= d&7)  (8 MB)

__device__ __forceinline__ void gload16(const void* g, void* l) {
    __builtin_amdgcn_global_load_lds(
        (const __attribute__((address_space(1))) unsigned int*)g,
        (__attribute__((address_space(3))) unsigned int*)l, 16, 0, 0);
}

__device__ __forceinline__ unsigned int pk2(float a, float b) {
    union { __bf16 h; unsigned short u; } x, y;
    x.h = (__bf16)a; y.h = (__bf16)b;
    return (unsigned int)x.u | ((unsigned int)y.u << 16);
}

__device__ __forceinline__ float exp2fast(float x) {
    return __builtin_amdgcn_exp2f(x);   // v_exp_f32: D = 2^S0
}

// ---------------- Kernel A: cache update + fused swizzled bf16 K pack ----------------
__global__ __launch_bounds__(256) void cache_update_kernel(
    const float4* __restrict__ kn, const float4* __restrict__ vn,
    const float4* __restrict__ pk, const float4* __restrict__ pv,
    const int* __restrict__ bp_p, const int* __restrict__ sp_p,
    float4* __restrict__ ok, float4* __restrict__ ov,
    __bf16* __restrict__ kbf)
{
    int i = blockIdx.x * 256 + threadIdx.x;      // float4 index, 4,194,304 total
    int bp = *bp_p, sp = *sp_p;
    int d4  = i & 31;
    int pos = (i >> 5) & 4095;
    int kvh = (i >> 17) & 7;
    int b   = i >> 20;
    float4 kv4, vv4;
    if (b == bp && pos >= sp && pos < sp + QL) {
        int ns = (kvh * QL + (pos - sp)) * 32 + d4;
        kv4 = kn[ns]; vv4 = vn[ns];
    } else {
        kv4 = pk[i]; vv4 = pv[i];
    }
    ok[i] = kv4; ov[i] = vv4;
    if (b == bp) {
        bf16x4 o;
        o[0] = (__bf16)kv4.x; o[1] = (__bf16)kv4.y;
        o[2] = (__bf16)kv4.z; o[3] = (__bf16)kv4.w;
        int c16 = d4 >> 1, half = d4 & 1;
        *(bf16x4*)(kbf + ((size_t)kvh * MS + pos) * HD
                       + ((c16 ^ (pos & 7)) * 8 + half * 4)) = o;
    }
}

// ---------------- Kernel B: V^T swizzled bf16 pack (tile-contiguous) ----------------
__global__ __launch_bounds__(256) void v_transpose_kernel(
    const float* __restrict__ vn, const float* __restrict__ pv,
    const int* __restrict__ bp_p, const int* __restrict__ sp_p,
    __bf16* __restrict__ vt)
{
    __shared__ __bf16 tile[64][132];
    int blk = blockIdx.x;
    int kvh = blk >> 6;
    int pt  = blk & 63;
    int bp = *bp_p, sp = *sp_p;
    int r0 = threadIdx.x >> 2;          // 0..63 (pos within tile)
    int cb = (threadIdx.x & 3) * 32;    // col base
    int pos = pt * 64 + r0;
    const float* src = (pos >= sp && pos < sp + QL)
        ? vn + ((size_t)kvh * QL + (pos - sp)) * HD + cb
        : pv + (((size_t)(bp * KVHN) + kvh) * MS + pos) * HD + cb;
    #pragma unroll
    for (int j = 0; j < 8; ++j) {
        float4 f = *(const float4*)(src + j * 4);
        bf16x4 o;
        o[0] = (__bf16)f.x; o[1] = (__bf16)f.y; o[2] = (__bf16)f.z; o[3] = (__bf16)f.w;
        *(bf16x4*)(&tile[r0][cb + j * 4]) = o;
    }
    __syncthreads();
    #pragma unroll
    for (int p = 0; p < 4; ++p) {
        int u = threadIdx.x + p * 256;
        int d = u >> 3; int chk = u & 7;
        bf16x8 v;
        #pragma unroll
        for (int j = 0; j < 8; ++j) v[j] = tile[chk * 8 + j][d];
        *(bf16x8*)(vt + (((size_t)kvh * 64 + pt) * HD + d) * 64
                      + ((chk ^ (d & 7)) * 8)) = v;
    }
}

// ---------------- Kernel C: swapped-operand 32x32 flash attention, KV-split waves ----
// grid = 512 (XCD-mapped), block = 256 (4 waves: qsub x kvhalf), super-tile = 64 kv
__global__ __launch_bounds__(256, 2) void attn_kernel(
    const float* __restrict__ q,
    const int* __restrict__ sp_p,
    const float* __restrict__ scale_p,
    const __bf16* __restrict__ kbf, const __bf16* __restrict__ vt,
    float* __restrict__ out)
{
    __shared__ __align__(16) unsigned char smem[65536];   // 2 x {K 16K | V 16K}

    const int sp = *sp_p;
    const float scl = *scale_p * 1.44269504088896340736f;  // fold log2(e): exp2 domain

    // XCD-aware decode: bid%8 == kvh so each XCD owns one kv-head (4MB = L2)
    int bid = blockIdx.x;
    int kvh = bid & 7;
    int inner = (bid & 255) >> 3;       // 0..31
    int headLocal = inner & 3;
    int j = inner >> 2;                 // 0..7
    int qtile = (bid < 256) ? j : 15 - j;   // bid and bid+256 pair long+short
    int head = kvh * 4 + headLocal;

    const int q0     = qtile * 64;
    const int tid    = threadIdx.x;
    const int wave   = tid >> 6;
    const int qsub   = wave & 1;        // which 32 q-rows
    const int kvhalf = wave >> 1;       // which 32-kv half of each super-tile
    const int lane   = tid & 63;
    const int hi     = lane >> 5;
    const int c31    = lane & 31;
    const int qb     = q0 + qsub * 32;
    const int myq    = qb + c31;

    const unsigned char* krow = (const unsigned char*)(kbf + (size_t)kvh * MS * HD);
    const unsigned char* vrow = (const unsigned char*)(vt + (size_t)kvh * 64 * HD * 64);

    // ---- Q B-fragments (hoisted, scale*log2e folded) ----
    bf16x8 qf[8];
    #pragma unroll
    for (int dc = 0; dc < 8; ++dc) {
        const float* src = q + ((size_t)(head * QL + qb + c31) * HD + dc * 16 + hi * 8);
        float4 f0 = *(const float4*)src;
        float4 f1 = *(const float4*)(src + 4);
        bf16x8 v;
        v[0]=(__bf16)(f0.x*scl); v[1]=(__bf16)(f0.y*scl);
        v[2]=(__bf16)(f0.z*scl); v[3]=(__bf16)(f0.w*scl);
        v[4]=(__bf16)(f1.x*scl); v[5]=(__bf16)(f1.y*scl);
        v[6]=(__bf16)(f1.z*scl); v[7]=(__bf16)(f1.w*scl);
        qf[dc] = v;
    }

    f32x16 acc[4];
    #pragma unroll
    for (int dsub = 0; dsub < 4; ++dsub)
        #pragma unroll
        for (int r = 0; r < 16; ++r) acc[dsub][r] = 0.f;
    float m_run = -1e30f, l_run = 0.f;

    const int n_super = (sp + q0 + 64) >> 6;

    auto stage = [&](int buf, int t) {
        const unsigned char* kt = krow + (size_t)t * 16384;
        const unsigned char* vtile = vrow + (size_t)t * 16384;
        unsigned char* kl = smem + buf * 32768;
        unsigned char* vl = kl + 16384;
        #pragma unroll
        for (int p = 0; p < 4; ++p) {
            int off = p * 4096 + tid * 16;
            gload16(kt + off, kl + off);
            gload16(vtile + off, vl + off);
        }
    };

    int cur = 0;
    stage(0, 0);
    __syncthreads();

    for (int it = 0; it < n_super; ++it) {
        const int n0 = it * KVB + kvhalf * 32;   // this wave's 32-kv window
        if (it + 1 < n_super) stage(cur ^ 1, it + 1);

        const unsigned char* Ksm = smem + cur * 32768;
        const unsigned char* Vsm = Ksm + 16384;

        // ---- QK^T (swapped): st = K(32kv x 128d) . Q^T(128d x 32q) ----
        f32x16 st;
        #pragma unroll
        for (int r = 0; r < 16; ++r) st[r] = 0.f;
        int kr = kvhalf * 32 + c31;
        __builtin_amdgcn_s_setprio(1);
        #pragma unroll
        for (int dc = 0; dc < 8; ++dc) {
            bf16x8 kf = *(const bf16x8*)(Ksm + kr * 256 + (((2 * dc + hi) ^ (kr & 7)) << 4));
            st = __builtin_amdgcn_mfma_f32_32x32x16_bf16(kf, qf[dc], st, 0, 0, 0);
        }
        __builtin_amdgcn_s_setprio(0);

        // ---- mask + in-register row max ----
        const bool need_mask = (n0 + 31) > (sp + qb);
        float mx = -1e30f;
        #pragma unroll
        for (int r = 0; r < 16; ++r) {
            if (need_mask) {
                int kvg = n0 + (r & 3) + 8 * (r >> 2) + 4 * hi;
                if (kvg > sp + myq) st[r] = -1e30f;
            }
            mx = fmaxf(mx, st[r]);
        }
        mx = fmaxf(mx, __shfl_xor(mx, 32));

        // ---- defer-max rescale (rare), exp2 domain ----
        if (!__all(mx <= m_run + 8.0f)) {
            float nm = fmaxf(m_run, mx);
            float corr = exp2fast(m_run - nm);
            m_run = nm;
            l_run *= corr;
            #pragma unroll
            for (int r = 0; r < 16; ++r) {
                int qsrc = (r & 3) + 8 * (r >> 2) + 4 * hi;
                float cq = __shfl(corr, qsrc);
                acc[0][r] *= cq; acc[1][r] *= cq; acc[2][r] *= cq; acc[3][r] *= cq;
            }
        }

        // ---- exp2 + sum (in-register) ----
        float lsum = 0.f;
        #pragma unroll
        for (int r = 0; r < 16; ++r) {
            float pv = exp2fast(st[r] - m_run);
            st[r] = pv;
            lsum += pv;
        }
        l_run += lsum;

        // ---- pack P to bf16, exchange halves, assemble PA frags A[m=q][k=kv] ----
        unsigned int loW[4], hiW[4];
        #pragma unroll
        for (int qd = 0; qd < 2; ++qd) {
            int b = qd * 8;
            loW[qd*2+0] = pk2(st[b+0], st[b+1]);
            loW[qd*2+1] = pk2(st[b+2], st[b+3]);
            hiW[qd*2+0] = pk2(st[b+4], st[b+5]);
            hiW[qd*2+1] = pk2(st[b+6], st[b+7]);
        }
        bf16x8 pfrag[2];
        #pragma unroll
        for (int qd = 0; qd < 2; ++qd) {
            unsigned int own0 = hi ? hiW[qd*2+0] : loW[qd*2+0];
            unsigned int own1 = hi ? hiW[qd*2+1] : loW[qd*2+1];
            unsigned int xm0  = hi ? loW[qd*2+0] : hiW[qd*2+0];
            unsigned int xm1  = hi ? loW[qd*2+1] : hiW[qd*2+1];
            unsigned int rc0 = __shfl_xor(xm0, 32);
            unsigned int rc1 = __shfl_xor(xm1, 32);
            union { unsigned int u[4]; bf16x8 v; } fu;
            fu.u[0] = hi ? rc0 : own0;
            fu.u[1] = hi ? rc1 : own1;
            fu.u[2] = hi ? own0 : rc0;
            fu.u[3] = hi ? own1 : rc1;
            pfrag[qd] = fu.v;
        }

        // ---- PV: O(32q x 128d) += P(32x32) . V(32x128) on this kv half ----
        __builtin_amdgcn_s_setprio(1);
        #pragma unroll
        for (int dsub = 0; dsub < 4; ++dsub) {
            int vr = dsub * 32 + c31;
            #pragma unroll
            for (int qd = 0; qd < 2; ++qd) {
                int ksg = kvhalf * 2 + qd;
                bf16x8 vf = *(const bf16x8*)(Vsm + vr * 128 + (((ksg * 2 + hi) ^ (vr & 7)) << 4));
                acc[dsub] = __builtin_amdgcn_mfma_f32_32x32x16_bf16(pfrag[qd], vf, acc[dsub], 0, 0, 0);
            }
        }
        __builtin_amdgcn_s_setprio(0);

        __syncthreads();
        cur ^= 1;
    }

    // ---- epilogue: merge kv-half pairs via LDS, normalize, store ----
    float l_full = l_run + __shfl_xor(l_run, 32);
    float* mlm = (float*)smem;            // [4][32] running max
    float* mll = (float*)smem + 128;      // [4][32] denom
    if (hi == 0) { mlm[wave * 32 + c31] = m_run; mll[wave * 32 + c31] = l_full; }
    __syncthreads();
    int pw = wave ^ 2;
    float m_o = mlm[pw * 32 + c31];
    float l_o = mll[pw * 32 + c31];
    float m_n = fmaxf(m_run, m_o);
    float sc   = exp2fast(m_run - m_n);
    float sc_o = exp2fast(m_o - m_n);
    float linv = 1.0f / (l_full * sc + l_o * sc_o);
    float* Oex = (float*)(smem + 1024) + (size_t)qsub * 32 * 128;
    if (kvhalf) {
        #pragma unroll
        for (int r = 0; r < 16; ++r) {
            int qsrc = (r & 3) + 8 * (r >> 2) + 4 * hi;
            float s = __shfl(sc, qsrc);
            #pragma unroll
            for (int dsub = 0; dsub < 4; ++dsub)
                Oex[qsrc * 128 + dsub * 32 + c31] = acc[dsub][r] * s;
        }
    }
    __syncthreads();
    if (!kvhalf) {
        #pragma unroll
        for (int r = 0; r < 16; ++r) {
            int qsrc = (r & 3) + 8 * (r >> 2) + 4 * hi;
            float s  = __shfl(sc, qsrc);
            float lq = __shfl(linv, qsrc);
            float* orow = out + (size_t)(qb + qsrc) * (NH * HD) + head * HD;
            #pragma unroll
            for (int dsub = 0; dsub < 4; ++dsub)
                orow[dsub * 32 + c31] =
                    (acc[dsub][r] * s + Oex[qsrc * 128 + dsub * 32 + c31]) * lq;
        }
    }
}

// ---------------- launch ----------------
extern "C" void kernel_launch(void* const* d_in, const int* in_sizes, int n_in,
                              void* d_out, int out_size, void* d_ws, size_t ws_size,
                              hipStream_t stream)
{
    const float* q_st   = (const float*)d_in[0];
    const float* k_new  = (const float*)d_in[1];
    const float* v_new  = (const float*)d_in[2];
    const int*   bp_p   = (const int*)d_in[4];
    const float* past_k = (const float*)d_in[5];
    const float* past_v = (const float*)d_in[6];
    const int*   sp_p   = (const int*)d_in[7];
    const float* scl_p  = (const float*)d_in[8];

    float* out_attn = (float*)d_out;                       // [1024][4096]
    float* out_k    = out_attn + (size_t)QL * NH * HD;     // [4][8][4096][128]
    float* out_v    = out_k + (size_t)4 * KVHN * MS * HD;

    __bf16* kbf = (__bf16*)d_ws;                           // [8][4096][128] swizzled
    __bf16* vtw = kbf + (size_t)KVHN * MS * HD;            // [8][64][128][64] swizzled

    cache_update_kernel<<<16384, 256, 0, stream>>>(
        (const float4*)k_new, (const float4*)v_new,
        (const float4*)past_k, (const float4*)past_v,
        bp_p, sp_p, (float4*)out_k, (float4*)out_v, kbf);

    v_transpose_kernel<<<512, 256, 0, stream>>>(
        v_new, past_v, bp_p, sp_p, vtw);

    attn_kernel<<<512, 256, 0, stream>>>(
        q_st, sp_p, scl_p, kbf, vtw, out_attn);
}

// Round 7
// 106.340 us; speedup vs baseline: 1.5549x; 1.0334x over previous
//
#include <hip/hip_runtime.h>

#define NH 32
#define KVHN 8
#define HD 128
#define QL 1024
#define MS 4096
#define KVB 64

typedef __bf16 bf16x8 __attribute__((ext_vector_type(8)));
typedef __bf16 bf16x4 __attribute__((ext_vector_type(4)));
typedef float f32x4 __attribute__((ext_vector_type(4)));
typedef float f32x16 __attribute__((ext_vector_type(16)));

// ws: Kbf [8][4096][128] bf16, rows pre-swizzled (chunk16 ^= pos&7)      (8 MB)
//     Vt  [8][64 tiles][128 d][64 kv] bf16, pre-swizzled (chunk ^= d&7)  (8 MB)

__device__ __forceinline__ void gload16(const void* g, void* l) {
    __builtin_amdgcn_global_load_lds(
        (const __attribute__((address_space(1))) unsigned int*)g,
        (__attribute__((address_space(3))) unsigned int*)l, 16, 0, 0);
}

__device__ __forceinline__ unsigned int pk2(float a, float b) {
    union { __bf16 h; unsigned short u; } x, y;
    x.h = (__bf16)a; y.h = (__bf16)b;
    return (unsigned int)x.u | ((unsigned int)y.u << 16);
}

__device__ __forceinline__ float exp2fast(float x) {
    return __builtin_amdgcn_exp2f(x);   // v_exp_f32: D = 2^S0
}

// ---------------- Kernel A: cache update + bf16 K pack + swizzled V^T pack ----------
// block = 256 threads = one (b, kvh, 8-pos) slice; pos stride: tid>>5, d4 = tid&31
__global__ __launch_bounds__(256) void cache_update_kernel(
    const float4* __restrict__ kn, const float4* __restrict__ vn,
    const float4* __restrict__ pk, const float4* __restrict__ pv,
    const int* __restrict__ bp_p, const int* __restrict__ sp_p,
    float4* __restrict__ ok, float4* __restrict__ ov,
    __bf16* __restrict__ kbf, __bf16* __restrict__ vt)
{
    __shared__ float vtile[8][132];               // padded: column reads conflict-free
    int i = blockIdx.x * 256 + threadIdx.x;      // float4 index, 4,194,304 total
    int bp = *bp_p, sp = *sp_p;
    int d4  = i & 31;
    int pos = (i >> 5) & 4095;
    int kvh = (i >> 17) & 7;
    int b   = i >> 20;
    float4 kv4, vv4;
    if (b == bp && pos >= sp && pos < sp + QL) {
        int ns = (kvh * QL + (pos - sp)) * 32 + d4;
        kv4 = kn[ns]; vv4 = vn[ns];
    } else {
        kv4 = pk[i]; vv4 = pv[i];
    }
    ok[i] = kv4; ov[i] = vv4;
    if (b == bp) {
        bf16x4 o;
        o[0] = (__bf16)kv4.x; o[1] = (__bf16)kv4.y;
        o[2] = (__bf16)kv4.z; o[3] = (__bf16)kv4.w;
        int c16 = d4 >> 1, half = d4 & 1;
        *(bf16x4*)(kbf + ((size_t)kvh * MS + pos) * HD
                       + ((c16 ^ (pos & 7)) * 8 + half * 4)) = o;
        *(float4*)&vtile[threadIdx.x >> 5][d4 * 4] = vv4;   // 528B row stride, 16B aligned
    }
    __syncthreads();
    if (b == bp && threadIdx.x < 128) {
        int d  = threadIdx.x;
        int p0 = (blockIdx.x * 8) & 4095;        // block's first pos (multiple of 8)
        int pt = p0 >> 6, chk = (p0 & 63) >> 3;
        bf16x8 o;
        #pragma unroll
        for (int j = 0; j < 8; ++j) o[j] = (__bf16)vtile[j][d];
        *(bf16x8*)(vt + (((size_t)kvh * 64 + pt) * HD + d) * 64
                      + ((chk ^ (d & 7)) * 8)) = o;
    }
}

// ---------------- Kernel C: swapped-operand 32x32 flash attention, KV-split waves ----
// grid = 512 (XCD-mapped), block = 256 (4 waves: qsub x kvhalf), super-tile = 64 kv
__global__ __launch_bounds__(256, 2) void attn_kernel(
    const float* __restrict__ q,
    const int* __restrict__ sp_p,
    const float* __restrict__ scale_p,
    const __bf16* __restrict__ kbf, const __bf16* __restrict__ vt,
    float* __restrict__ out)
{
    __shared__ __align__(16) unsigned char smem[65536];   // 2 x {K 16K | V 16K}

    const int sp = *sp_p;
    const float scl = *scale_p * 1.44269504088896340736f;  // fold log2(e): exp2 domain

    // XCD-aware decode: bid%8 == kvh so each XCD owns one kv-head (4MB = L2)
    int bid = blockIdx.x;
    int kvh = bid & 7;
    int inner = (bid & 255) >> 3;       // 0..31
    int headLocal = inner & 3;
    int j = inner >> 2;                 // 0..7
    int qtile = (bid < 256) ? j : 15 - j;   // bid and bid+256 pair long+short
    int head = kvh * 4 + headLocal;

    const int q0     = qtile * 64;
    const int tid    = threadIdx.x;
    const int wave   = tid >> 6;
    const int qsub   = wave & 1;        // which 32 q-rows
    const int kvhalf = wave >> 1;       // which 32-kv half of each super-tile
    const int lane   = tid & 63;
    const int hi     = lane >> 5;
    const int c31    = lane & 31;
    const int qb     = q0 + qsub * 32;
    const int myq    = qb + c31;

    const unsigned char* krow = (const unsigned char*)(kbf + (size_t)kvh * MS * HD);
    const unsigned char* vrow = (const unsigned char*)(vt + (size_t)kvh * 64 * HD * 64);

    // ---- Q B-fragments (hoisted, scale*log2e folded) ----
    bf16x8 qf[8];
    #pragma unroll
    for (int dc = 0; dc < 8; ++dc) {
        const float* src = q + ((size_t)(head * QL + qb + c31) * HD + dc * 16 + hi * 8);
        float4 f0 = *(const float4*)src;
        float4 f1 = *(const float4*)(src + 4);
        bf16x8 v;
        v[0]=(__bf16)(f0.x*scl); v[1]=(__bf16)(f0.y*scl);
        v[2]=(__bf16)(f0.z*scl); v[3]=(__bf16)(f0.w*scl);
        v[4]=(__bf16)(f1.x*scl); v[5]=(__bf16)(f1.y*scl);
        v[6]=(__bf16)(f1.z*scl); v[7]=(__bf16)(f1.w*scl);
        qf[dc] = v;
    }

    f32x16 acc[4];
    #pragma unroll
    for (int dsub = 0; dsub < 4; ++dsub)
        #pragma unroll
        for (int r = 0; r < 16; ++r) acc[dsub][r] = 0.f;
    float m_run = -1e30f, l_run = 0.f;

    const int n_super = (sp + q0 + 64) >> 6;

    auto stage = [&](int buf, int t) {
        const unsigned char* kt = krow + (size_t)t * 16384;
        const unsigned char* vtile = vrow + (size_t)t * 16384;
        unsigned char* kl = smem + buf * 32768;
        unsigned char* vl = kl + 16384;
        #pragma unroll
        for (int p = 0; p < 4; ++p) {
            int off = p * 4096 + tid * 16;
            gload16(kt + off, kl + off);
            gload16(vtile + off, vl + off);
        }
    };

    int cur = 0;
    stage(0, 0);
    __syncthreads();

    for (int it = 0; it < n_super; ++it) {
        const int n0 = it * KVB + kvhalf * 32;   // this wave's 32-kv window
        if (it + 1 < n_super) stage(cur ^ 1, it + 1);

        const unsigned char* Ksm = smem + cur * 32768;
        const unsigned char* Vsm = Ksm + 16384;

        // ---- QK^T (swapped): two independent 4-deep MFMA chains ----
        f32x16 st0, st1;
        #pragma unroll
        for (int r = 0; r < 16; ++r) { st0[r] = 0.f; st1[r] = 0.f; }
        int kr = kvhalf * 32 + c31;
        __builtin_amdgcn_s_setprio(1);
        #pragma unroll
        for (int dc = 0; dc < 4; ++dc) {
            bf16x8 ka = *(const bf16x8*)(Ksm + kr * 256 + (((2 * dc + hi) ^ (kr & 7)) << 4));
            st0 = __builtin_amdgcn_mfma_f32_32x32x16_bf16(ka, qf[dc], st0, 0, 0, 0);
            bf16x8 kb = *(const bf16x8*)(Ksm + kr * 256 + (((2 * (dc + 4) + hi) ^ (kr & 7)) << 4));
            st1 = __builtin_amdgcn_mfma_f32_32x32x16_bf16(kb, qf[dc + 4], st1, 0, 0, 0);
        }
        __builtin_amdgcn_s_setprio(0);
        f32x16 st = st0 + st1;

        // ---- mask + in-register row max (pairwise tree) ----
        const bool need_mask = (n0 + 31) > (sp + qb);
        if (need_mask) {
            #pragma unroll
            for (int r = 0; r < 16; ++r) {
                int kvg = n0 + (r & 3) + 8 * (r >> 2) + 4 * hi;
                if (kvg > sp + myq) st[r] = -1e30f;
            }
        }
        float m01 = fmaxf(fmaxf(st[0], st[1]), fmaxf(st[2], st[3]));
        float m23 = fmaxf(fmaxf(st[4], st[5]), fmaxf(st[6], st[7]));
        float m45 = fmaxf(fmaxf(st[8], st[9]), fmaxf(st[10], st[11]));
        float m67 = fmaxf(fmaxf(st[12], st[13]), fmaxf(st[14], st[15]));
        float mx = fmaxf(fmaxf(m01, m23), fmaxf(m45, m67));
        mx = fmaxf(mx, __shfl_xor(mx, 32));

        // ---- defer-max rescale (rare), exp2 domain ----
        if (!__all(mx <= m_run + 8.0f)) {
            float nm = fmaxf(m_run, mx);
            float corr = exp2fast(m_run - nm);
            m_run = nm;
            l_run *= corr;
            #pragma unroll
            for (int r = 0; r < 16; ++r) {
                int qsrc = (r & 3) + 8 * (r >> 2) + 4 * hi;
                float cq = __shfl(corr, qsrc);
                acc[0][r] *= cq; acc[1][r] *= cq; acc[2][r] *= cq; acc[3][r] *= cq;
            }
        }

        // ---- exp2 + tree sum (in-register) ----
        #pragma unroll
        for (int r = 0; r < 16; ++r) st[r] = exp2fast(st[r] - m_run);
        {
            float s0 = (st[0] + st[1]) + (st[2] + st[3]);
            float s1 = (st[4] + st[5]) + (st[6] + st[7]);
            float s2 = (st[8] + st[9]) + (st[10] + st[11]);
            float s3 = (st[12] + st[13]) + (st[14] + st[15]);
            l_run += (s0 + s1) + (s2 + s3);
        }

        // ---- pack P to bf16, permlane32_swap half-exchange, assemble PA frags ----
        unsigned int loW[4], hiW[4];
        #pragma unroll
        for (int qd = 0; qd < 2; ++qd) {
            int b = qd * 8;
            loW[qd*2+0] = pk2(st[b+0], st[b+1]);
            loW[qd*2+1] = pk2(st[b+2], st[b+3]);
            hiW[qd*2+0] = pk2(st[b+4], st[b+5]);
            hiW[qd*2+1] = pk2(st[b+6], st[b+7]);
        }
        bf16x8 pfrag[2];
        #pragma unroll
        for (int qd = 0; qd < 2; ++qd) {
            unsigned int a0 = loW[qd*2+0], b0 = hiW[qd*2+0];
            unsigned int a1 = loW[qd*2+1], b1 = hiW[qd*2+1];
            // swap(a,b): a' = {a.lo, b.lo}, b' = {a.hi, b.hi}
            asm("v_permlane32_swap_b32 %0, %1" : "+v"(a0), "+v"(b0));
            asm("v_permlane32_swap_b32 %0, %1" : "+v"(a1), "+v"(b1));
            union { unsigned int u[4]; bf16x8 v; } fu;
            fu.u[0] = a0; fu.u[1] = a1; fu.u[2] = b0; fu.u[3] = b1;
            pfrag[qd] = fu.v;
        }

        // ---- PV: O(32q x 128d) += P(32x32) . V(32x128) on this kv half ----
        __builtin_amdgcn_s_setprio(1);
        #pragma unroll
        for (int dsub = 0; dsub < 4; ++dsub) {
            int vr = dsub * 32 + c31;
            #pragma unroll
            for (int qd = 0; qd < 2; ++qd) {
                int ksg = kvhalf * 2 + qd;
                bf16x8 vf = *(const bf16x8*)(Vsm + vr * 128 + (((ksg * 2 + hi) ^ (vr & 7)) << 4));
                acc[dsub] = __builtin_amdgcn_mfma_f32_32x32x16_bf16(pfrag[qd], vf, acc[dsub], 0, 0, 0);
            }
        }
        __builtin_amdgcn_s_setprio(0);

        __syncthreads();
        cur ^= 1;
    }

    // ---- epilogue: merge kv-half pairs via LDS, normalize, store ----
    float l_full = l_run + __shfl_xor(l_run, 32);
    float* mlm = (float*)smem;            // [4][32] running max
    float* mll = (float*)smem + 128;      // [4][32] denom
    if (hi == 0) { mlm[wave * 32 + c31] = m_run; mll[wave * 32 + c31] = l_full; }
    __syncthreads();
    int pw = wave ^ 2;
    float m_o = mlm[pw * 32 + c31];
    float l_o = mll[pw * 32 + c31];
    float m_n = fmaxf(m_run, m_o);
    float sc   = exp2fast(m_run - m_n);
    float sc_o = exp2fast(m_o - m_n);
    float linv = 1.0f / (l_full * sc + l_o * sc_o);
    float* Oex = (float*)(smem + 1024) + (size_t)qsub * 32 * 128;
    if (kvhalf) {
        #pragma unroll
        for (int r = 0; r < 16; ++r) {
            int qsrc = (r & 3) + 8 * (r >> 2) + 4 * hi;
            float s = __shfl(sc, qsrc);
            #pragma unroll
            for (int dsub = 0; dsub < 4; ++dsub)
                Oex[qsrc * 128 + dsub * 32 + c31] = acc[dsub][r] * s;
        }
    }
    __syncthreads();
    if (!kvhalf) {
        #pragma unroll
        for (int r = 0; r < 16; ++r) {
            int qsrc = (r & 3) + 8 * (r >> 2) + 4 * hi;
            float s  = __shfl(sc, qsrc);
            float lq = __shfl(linv, qsrc);
            float* orow = out + (size_t)(qb + qsrc) * (NH * HD) + head * HD;
            #pragma unroll
            for (int dsub = 0; dsub < 4; ++dsub)
                orow[dsub * 32 + c31] =
                    (acc[dsub][r] * s + Oex[qsrc * 128 + dsub * 32 + c31]) * lq;
        }
    }
}

// ---------------- launch ----------------
extern "C" void kernel_launch(void* const* d_in, const int* in_sizes, int n_in,
                              void* d_out, int out_size, void* d_ws, size_t ws_size,
                              hipStream_t stream)
{
    const float* q_st   = (const float*)d_in[0];
    const float* k_new  = (const float*)d_in[1];
    const float* v_new  = (const float*)d_in[2];
    const int*   bp_p   = (const int*)d_in[4];
    const float* past_k = (const float*)d_in[5];
    const float* past_v = (const float*)d_in[6];
    const int*   sp_p   = (const int*)d_in[7];
    const float* scl_p  = (const float*)d_in[8];

    float* out_attn = (float*)d_out;                       // [1024][4096]
    float* out_k    = out_attn + (size_t)QL * NH * HD;     // [4][8][4096][128]
    float* out_v    = out_k + (size_t)4 * KVHN * MS * HD;

    __bf16* kbf = (__bf16*)d_ws;                           // [8][4096][128] swizzled
    __bf16* vtw = kbf + (size_t)KVHN * MS * HD;            // [8][64][128][64] swizzled

    cache_update_kernel<<<16384, 256, 0, stream>>>(
        (const float4*)k_new, (const float4*)v_new,
        (const float4*)past_k, (const float4*)past_v,
        bp_p, sp_p, (float4*)out_k, (float4*)out_v, kbf, vtw);

    attn_kernel<<<512, 256, 0, stream>>>(
        q_st, sp_p, scl_p, kbf, vtw, out_attn);
}